// Round 1
// baseline (107.632 us; speedup 1.0000x reference)
//
#include <hip/hip_runtime.h>

#define BATCH 8192
#define NG 3
#define NE 32
#define D 128

// One block per token, 128 threads (2 waves). Thread o owns output column o.
// x row staged in LDS; W rows read coalesced (thread o reads W[e][i][o],
// consecutive o -> consecutive addresses). Everything fp32.
__global__ __launch_bounds__(128) void moe_layer_kernel(
    const float* __restrict__ x,
    const int* __restrict__ genres,
    const float* __restrict__ W,
    float* __restrict__ out)
{
    const int b = blockIdx.x;
    const int o = threadIdx.x;

    __shared__ float xs[D];
    xs[o] = x[(size_t)b * D + o];
    __syncthreads();

    int e0 = genres[b * NG + 0];
    int e1 = genres[b * NG + 1];
    int e2 = genres[b * NG + 2];

    float acc = 0.0f;
    int cnt = 0;

    // block-uniform branches (all threads share b), no lane divergence
    #pragma unroll
    for (int g = 0; g < NG; ++g) {
        int e = (g == 0) ? e0 : (g == 1) ? e1 : e2;
        if (e != 0) {
            ++cnt;
            const float* We = W + (size_t)e * D * D + o;
            float a = 0.0f;
            #pragma unroll 8
            for (int i = 0; i < D; ++i) {
                a = fmaf(xs[i], We[(size_t)i * D], a);
            }
            acc += a;
        }
    }

    float r = (cnt > 0) ? (acc / (float)cnt) : 0.0f;
    out[(size_t)b * D + o] = (r >= 0.0f) ? r : 0.01f * r;
}

extern "C" void kernel_launch(void* const* d_in, const int* in_sizes, int n_in,
                              void* d_out, int out_size, void* d_ws, size_t ws_size,
                              hipStream_t stream)
{
    const float* x      = (const float*)d_in[0];
    const int*   genres = (const int*)d_in[1];
    const float* W0     = (const float*)d_in[2];
    const float* W1     = (const float*)d_in[3];
    float*       out    = (float*)d_out;

    // Layer-1 output buffer: prefer workspace; in-place on d_out is also safe
    // (block b only ever reads row b before writing row b).
    float* tmp = (ws_size >= (size_t)BATCH * D * sizeof(float)) ? (float*)d_ws
                                                                : out;

    moe_layer_kernel<<<BATCH, D, 0, stream>>>(x,   genres, W0, tmp);
    moe_layer_kernel<<<BATCH, D, 0, stream>>>(tmp, genres, W1, out);
}

// Round 2
// 82.738 us; speedup vs baseline: 1.3009x; 1.3009x over previous
//
#include <hip/hip_runtime.h>

#define BATCH 8192
#define NG 3
#define NE 32
#define D 128
#define NPAIR (BATCH * NG)   // 24576

#define TILE_T 64            // tokens per GEMM tile
#define KC 64                // K chunk staged in LDS
#define MAXTILES ((NPAIR + TILE_T - 1) / TILE_T)  // 384 worst case

// ---------------- workspace layout (bytes) ----------------
// [0, 256)                     : offsets int[NE+1]
// [256, 256+NPAIR*4)           : pair_bg int[NPAIR]
// [98560, +NPAIR*D*4)          : y float[NPAIR][D]
// [12681472, +BATCH*D*4)       : tmp1 float[BATCH][D]
#define OFF_OFFSETS 0
#define OFF_PAIR    256
#define OFF_Y       (OFF_PAIR + NPAIR * 4)              // 98560
#define OFF_TMP1    (OFF_Y + (size_t)NPAIR * D * 4)     // 12681472
#define WS_REQUIRED (OFF_TMP1 + (size_t)BATCH * D * 4)  // ~16.1 MiB

// ---------------- sort: bucket (token,slot) pairs by expert ----------------
// Single block, 1024 threads. Expert 0 = padding, excluded.
// Ordering within a bucket is atomic-scheduling-dependent, but every pair's
// GEMM result depends only on (token, expert), so the final output is
// invariant to ordering.
__global__ __launch_bounds__(1024) void moe_sort_kernel(
    const int* __restrict__ genres, int* __restrict__ offsets,
    int* __restrict__ pair_bg)
{
    __shared__ int scnt[NE];
    __shared__ int soff[NE + 1];
    __shared__ int scur[NE];
    const int tid = threadIdx.x;

    if (tid < NE) scnt[tid] = 0;
    __syncthreads();

    const int4* g4 = (const int4*)genres;
    const int n4 = NPAIR / 4;  // 6144
    for (int i = tid; i < n4; i += 1024) {
        int4 g = g4[i];
        if (g.x != 0) atomicAdd(&scnt[g.x], 1);
        if (g.y != 0) atomicAdd(&scnt[g.y], 1);
        if (g.z != 0) atomicAdd(&scnt[g.z], 1);
        if (g.w != 0) atomicAdd(&scnt[g.w], 1);
    }
    __syncthreads();

    if (tid == 0) {
        int run = 0;
        for (int e = 0; e < NE; ++e) { soff[e] = run; run += scnt[e]; }
        soff[NE] = run;
    }
    __syncthreads();

    if (tid < NE) { scur[tid] = soff[tid]; offsets[tid] = soff[tid]; }
    if (tid == 0) offsets[NE] = soff[NE];
    __syncthreads();

    for (int i = tid; i < n4; i += 1024) {
        int4 g = g4[i];
        int p = i * 4;
        if (g.x != 0) pair_bg[atomicAdd(&scur[g.x], 1)] = p + 0;
        if (g.y != 0) pair_bg[atomicAdd(&scur[g.y], 1)] = p + 1;
        if (g.z != 0) pair_bg[atomicAdd(&scur[g.z], 1)] = p + 2;
        if (g.w != 0) pair_bg[atomicAdd(&scur[g.w], 1)] = p + 3;
    }
}

// ---------------- grouped GEMM: y[pair] = x[token] @ W[expert] ----------------
// Block = 256 threads = (32 output-quads) x (8 token-groups of 8 tokens).
// Per block: 64-token tile of one expert's list; stages x[64][KC] + W[KC][128]
// per K-chunk. LDS = 32K + 16K + ~0.5K -> 3 blocks/CU.
__global__ __launch_bounds__(256, 3) void moe_gemm_kernel(
    const float* __restrict__ x,      // [BATCH][D]
    const float* __restrict__ W,      // [NE][D][D]
    const int* __restrict__ offsets,  // [NE+1]
    const int* __restrict__ pair_bg,  // [NPAIR]
    float* __restrict__ y)            // [NPAIR][D]
{
    const int e = blockIdx.y + 1;                 // experts 1..31
    const int start = offsets[e];
    const int end   = offsets[e + 1];
    const int tileStart = start + blockIdx.x * TILE_T;
    if (tileStart >= end) return;
    const int nt = min(TILE_T, end - tileStart);

    __shared__ __align__(16) float sW[KC][D];       // 32 KB
    __shared__ __align__(16) float sX[TILE_T][KC];  // 16 KB
    __shared__ int sBG[TILE_T];
    __shared__ int sRow[TILE_T];

    const int tid = threadIdx.x;
    if (tid < TILE_T) {
        int bg = (tid < nt) ? pair_bg[tileStart + tid] : 0;
        sBG[tid] = bg;
        sRow[tid] = (tid < nt) ? (bg / NG) : 0;   // token index; padded lanes read row 0
    }
    __syncthreads();

    const int ox = tid & 31;   // output quad: cols [4*ox, 4*ox+4)
    const int ty = tid >> 5;   // token group: rows [8*ty, 8*ty+8)

    float acc[8][4];
    #pragma unroll
    for (int t = 0; t < 8; ++t)
        #pragma unroll
        for (int j = 0; j < 4; ++j) acc[t][j] = 0.0f;

    const float* Wbase = W + (size_t)e * D * D;

    for (int kc = 0; kc < D; kc += KC) {
        // stage W chunk: KC*D = 8192 floats = 2048 float4; 8 per thread, coalesced
        #pragma unroll
        for (int i = 0; i < 8; ++i) {
            int f4 = tid + i * 256;
            int kr = f4 >> 5;          // D/4 = 32 float4 per row
            int c4 = f4 & 31;
            *(float4*)&sW[kr][c4 * 4] =
                *(const float4*)&Wbase[(size_t)(kc + kr) * D + c4 * 4];
        }
        // stage x chunk: TILE_T*KC = 4096 floats = 1024 float4; 4 per thread
        #pragma unroll
        for (int i = 0; i < 4; ++i) {
            int f4 = tid + i * 256;
            int r  = f4 >> 4;          // KC/4 = 16 float4 per row
            int c4 = f4 & 15;
            *(float4*)&sX[r][c4 * 4] =
                *(const float4*)&x[(size_t)sRow[r] * D + kc + c4 * 4];
        }
        __syncthreads();

        #pragma unroll
        for (int k = 0; k < KC; k += 4) {
            float4 w0 = *(float4*)&sW[k + 0][ox * 4];
            float4 w1 = *(float4*)&sW[k + 1][ox * 4];
            float4 w2 = *(float4*)&sW[k + 2][ox * 4];
            float4 w3 = *(float4*)&sW[k + 3][ox * 4];
            #pragma unroll
            for (int t = 0; t < 8; ++t) {
                float4 xv = *(float4*)&sX[ty * 8 + t][k];
                acc[t][0] = fmaf(xv.x, w0.x, fmaf(xv.y, w1.x, fmaf(xv.z, w2.x, fmaf(xv.w, w3.x, acc[t][0]))));
                acc[t][1] = fmaf(xv.x, w0.y, fmaf(xv.y, w1.y, fmaf(xv.z, w2.y, fmaf(xv.w, w3.y, acc[t][1]))));
                acc[t][2] = fmaf(xv.x, w0.z, fmaf(xv.y, w1.z, fmaf(xv.z, w2.z, fmaf(xv.w, w3.z, acc[t][2]))));
                acc[t][3] = fmaf(xv.x, w0.w, fmaf(xv.y, w1.w, fmaf(xv.z, w2.w, fmaf(xv.w, w3.w, acc[t][3]))));
            }
        }
        __syncthreads();
    }

    #pragma unroll
    for (int t = 0; t < 8; ++t) {
        int tok = ty * 8 + t;
        if (tok < nt) {
            int bg = sBG[tok];
            float4 v = make_float4(acc[t][0], acc[t][1], acc[t][2], acc[t][3]);
            *(float4*)&y[(size_t)bg * D + ox * 4] = v;
        }
    }
}

// ---------------- combine: out[b] = lrelu(sum_g mask*y[b,g] / cnt) ----------------
__global__ __launch_bounds__(256) void moe_combine_kernel(
    const float* __restrict__ y, const int* __restrict__ genres,
    float* __restrict__ out)
{
    int gid = blockIdx.x * blockDim.x + threadIdx.x;  // over BATCH*32
    int b  = gid >> 5;
    int o4 = (gid & 31) * 4;

    int g0 = genres[b * NG + 0];
    int g1 = genres[b * NG + 1];
    int g2 = genres[b * NG + 2];

    float4 s = make_float4(0.f, 0.f, 0.f, 0.f);
    int cnt = 0;
    if (g0 != 0) { float4 v = *(const float4*)&y[((size_t)b * NG + 0) * D + o4]; s.x += v.x; s.y += v.y; s.z += v.z; s.w += v.w; ++cnt; }
    if (g1 != 0) { float4 v = *(const float4*)&y[((size_t)b * NG + 1) * D + o4]; s.x += v.x; s.y += v.y; s.z += v.z; s.w += v.w; ++cnt; }
    if (g2 != 0) { float4 v = *(const float4*)&y[((size_t)b * NG + 2) * D + o4]; s.x += v.x; s.y += v.y; s.z += v.z; s.w += v.w; ++cnt; }

    float inv = (cnt > 0) ? (1.0f / (float)cnt) : 0.0f;
    float4 r;
    r.x = s.x * inv; r.y = s.y * inv; r.z = s.z * inv; r.w = s.w * inv;
    r.x = (r.x >= 0.f) ? r.x : 0.01f * r.x;
    r.y = (r.y >= 0.f) ? r.y : 0.01f * r.y;
    r.z = (r.z >= 0.f) ? r.z : 0.01f * r.z;
    r.w = (r.w >= 0.f) ? r.w : 0.01f * r.w;
    *(float4*)&out[(size_t)b * D + o4] = r;
}

// ---------------- fallback (round-0 kernel) if ws is too small ----------------
__global__ __launch_bounds__(128) void moe_layer_kernel(
    const float* __restrict__ x, const int* __restrict__ genres,
    const float* __restrict__ W, float* __restrict__ out)
{
    const int b = blockIdx.x;
    const int o = threadIdx.x;
    __shared__ float xs[D];
    xs[o] = x[(size_t)b * D + o];
    __syncthreads();
    int e0 = genres[b * NG + 0], e1 = genres[b * NG + 1], e2 = genres[b * NG + 2];
    float acc = 0.0f; int cnt = 0;
    #pragma unroll
    for (int g = 0; g < NG; ++g) {
        int e = (g == 0) ? e0 : (g == 1) ? e1 : e2;
        if (e != 0) {
            ++cnt;
            const float* We = W + (size_t)e * D * D + o;
            float a = 0.0f;
            #pragma unroll 8
            for (int i = 0; i < D; ++i) a = fmaf(xs[i], We[(size_t)i * D], a);
            acc += a;
        }
    }
    float r = (cnt > 0) ? (acc / (float)cnt) : 0.0f;
    out[(size_t)b * D + o] = (r >= 0.0f) ? r : 0.01f * r;
}

extern "C" void kernel_launch(void* const* d_in, const int* in_sizes, int n_in,
                              void* d_out, int out_size, void* d_ws, size_t ws_size,
                              hipStream_t stream)
{
    const float* x      = (const float*)d_in[0];
    const int*   genres = (const int*)d_in[1];
    const float* W0     = (const float*)d_in[2];
    const float* W1     = (const float*)d_in[3];
    float*       out    = (float*)d_out;

    if (ws_size < WS_REQUIRED) {
        // fallback: per-token kernels (round-0 path)
        float* tmp = out;
        moe_layer_kernel<<<BATCH, D, 0, stream>>>(x,   genres, W0, tmp);
        moe_layer_kernel<<<BATCH, D, 0, stream>>>(tmp, genres, W1, out);
        return;
    }

    char* ws = (char*)d_ws;
    int*   offsets = (int*)(ws + OFF_OFFSETS);
    int*   pair_bg = (int*)(ws + OFF_PAIR);
    float* y       = (float*)(ws + OFF_Y);
    float* tmp1    = (float*)(ws + OFF_TMP1);

    moe_sort_kernel<<<1, 1024, 0, stream>>>(genres, offsets, pair_bg);

    dim3 ggrid(MAXTILES, NE - 1);
    moe_gemm_kernel<<<ggrid, 256, 0, stream>>>(x, W0, offsets, pair_bg, y);
    moe_combine_kernel<<<(BATCH * 32) / 256, 256, 0, stream>>>(y, genres, tmp1);
    moe_gemm_kernel<<<ggrid, 256, 0, stream>>>(tmp1, W1, offsets, pair_bg, y);
    moe_combine_kernel<<<(BATCH * 32) / 256, 256, 0, stream>>>(y, genres, out);
}

// Round 3
// 61.565 us; speedup vs baseline: 1.7483x; 1.3439x over previous
//
#include <hip/hip_runtime.h>

#define BATCH 8192
#define NG 3
#define NE 32
#define D 128
#define NPAIR (BATCH * NG)          // 24576
#define TILE 32                     // tokens per GEMM tile
#define KC 64                       // K chunk staged in LDS
#define MAXT (NPAIR / TILE + NE - 1) // 799 worst-case tiles

// ---------------- workspace layout (bytes) ----------------
#define OFF_HIST  0                 // int[32]
#define OFF_GCUR  128               // int[32]
#define OFF_NT    256               // int (numTiles)
#define OFF_TILES 512               // int4[MAXT]  (12784 B)
#define OFF_PAIR  16384             // int[NPAIR]  (98304 B)
#define OFF_Y     (OFF_PAIR + NPAIR * 4)            // 114688
#define OFF_TMP1  (OFF_Y + (size_t)NPAIR * D * 4)   // 12697600
#define WS_REQUIRED (OFF_TMP1 + (size_t)BATCH * D * 4)

// ---------------- init: zero the global histogram ----------------
__global__ void moe_init_kernel(int* __restrict__ ghist)
{
    ghist[threadIdx.x] = 0;
}

// ---------------- histogram: per-block LDS hist -> global ----------------
__global__ __launch_bounds__(256) void moe_hist_kernel(
    const int* __restrict__ genres, int* __restrict__ ghist)
{
    __shared__ int sh[NE];
    const int tid = threadIdx.x;
    if (tid < NE) sh[tid] = 0;
    __syncthreads();
    const int g = genres[blockIdx.x * 256 + tid];
    if (g != 0) atomicAdd(&sh[g], 1);
    __syncthreads();
    if (tid < NE && sh[tid] > 0) atomicAdd(&ghist[tid], sh[tid]);
}

// ---------------- scan + tile build (1 block, 64 threads) ----------------
__global__ void moe_scan_tiles_kernel(
    const int* __restrict__ ghist, int* __restrict__ gcur,
    int* __restrict__ nTiles, int4* __restrict__ tileInfo)
{
    const int e = threadIdx.x;                       // 0..63
    int cnt = (e > 0 && e < NE) ? ghist[e] : 0;      // expert 0 = padding
    int ntl = (cnt + TILE - 1) / TILE;
    int off = 0, tbase = 0, ttot = 0;
    for (int j = 0; j < NE; ++j) {
        int cj = __shfl(cnt, j, 64);
        int tj = __shfl(ntl, j, 64);
        if (j < e) { off += cj; tbase += tj; }
        ttot += tj;
    }
    if (e < NE) gcur[e] = off;
    if (e == 0) *nTiles = ttot;
    for (int t = 0; t < ntl; ++t) {
        int st = off + t * TILE;
        int rem = cnt - t * TILE;
        tileInfo[tbase + t] = make_int4(e, st, (rem < TILE) ? rem : TILE, 0);
    }
}

// ---------------- scatter: block-aggregated bucket write ----------------
// Within-bucket order is scheduling-dependent, but y is indexed by original
// pair id, so the final output is invariant to this order.
__global__ __launch_bounds__(256) void moe_scatter_kernel(
    const int* __restrict__ genres, int* __restrict__ gcur,
    int* __restrict__ pair_bg)
{
    __shared__ int shist[NE], sbase[NE], scur[NE];
    const int tid = threadIdx.x;
    if (tid < NE) { shist[tid] = 0; scur[tid] = 0; }
    __syncthreads();
    const int i = blockIdx.x * 256 + tid;
    const int g = genres[i];
    if (g != 0) atomicAdd(&shist[g], 1);
    __syncthreads();
    if (tid < NE && shist[tid] > 0) sbase[tid] = atomicAdd(&gcur[tid], shist[tid]);
    __syncthreads();
    if (g != 0) {
        int r = atomicAdd(&scur[g], 1);
        pair_bg[sbase[g] + r] = i;
    }
}

// ---------------- grouped GEMM: y[pair] = x[token] @ W[expert] ----------------
// 799-block fixed grid over dense tile list; 256 threads; LDS exactly 40960 B
// -> 4 blocks/CU = 16 waves/CU. Thread = (ox: 32 col-quads) x (ty: 8 groups
// of 4 tokens); acc[4 tok][4 col].
__global__ __launch_bounds__(256, 4) void moe_gemm_kernel(
    const float* __restrict__ x,        // [BATCH][D]
    const float* __restrict__ W,        // [NE][D][D]
    const int* __restrict__ pair_bg,    // [NPAIR] bucketed pair ids
    const int4* __restrict__ tileInfo,  // [MAXT]
    const int* __restrict__ nTiles,
    float* __restrict__ y)              // [NPAIR][D]
{
    if ((int)blockIdx.x >= *nTiles) return;
    const int4 ti = tileInfo[blockIdx.x];
    const int e = ti.x, start = ti.y, nt = ti.z;

    __shared__ __align__(16) float sW[KC][D];     // 32768 B
    __shared__ __align__(16) float sX[TILE][KC];  // 8192 B

    const int tid = threadIdx.x;
    const int ox = tid & 31;    // output col quad: cols [4*ox, 4*ox+4)
    const int ty = tid >> 5;    // token group: tokens [4*ty, 4*ty+4)

    float acc[4][4] = {{0.f,0.f,0.f,0.f},{0.f,0.f,0.f,0.f},
                       {0.f,0.f,0.f,0.f},{0.f,0.f,0.f,0.f}};

    const float* Wbase = W + (size_t)e * D * D;

    for (int kc = 0; kc < D; kc += KC) {
        // stage W chunk: KC*D/4 = 2048 float4, 8 per thread, coalesced
        #pragma unroll
        for (int i = 0; i < 8; ++i) {
            int f4 = tid + i * 256;
            int kr = f4 >> 5, c4 = f4 & 31;
            *(float4*)&sW[kr][c4 * 4] =
                *(const float4*)&Wbase[(size_t)(kc + kr) * D + c4 * 4];
        }
        // stage x chunk: TILE*KC/4 = 512 float4, 2 per thread; row via pair_bg
        #pragma unroll
        for (int i = 0; i < 2; ++i) {
            int f4 = tid + i * 256;
            int r = f4 >> 4, c4 = f4 & 15;
            int idx = start + ((r < nt) ? r : 0);
            int row = pair_bg[idx] / NG;           // 16 lanes share idx -> broadcast
            *(float4*)&sX[r][c4 * 4] =
                *(const float4*)&x[(size_t)row * D + kc + c4 * 4];
        }
        __syncthreads();

        #pragma unroll
        for (int k = 0; k < KC; k += 4) {
            float4 w0 = *(float4*)&sW[k + 0][ox * 4];
            float4 w1 = *(float4*)&sW[k + 1][ox * 4];
            float4 w2 = *(float4*)&sW[k + 2][ox * 4];
            float4 w3 = *(float4*)&sW[k + 3][ox * 4];
            #pragma unroll
            for (int t = 0; t < 4; ++t) {
                float4 xv = *(float4*)&sX[ty * 4 + t][k];
                acc[t][0] = fmaf(xv.x, w0.x, fmaf(xv.y, w1.x, fmaf(xv.z, w2.x, fmaf(xv.w, w3.x, acc[t][0]))));
                acc[t][1] = fmaf(xv.x, w0.y, fmaf(xv.y, w1.y, fmaf(xv.z, w2.y, fmaf(xv.w, w3.y, acc[t][1]))));
                acc[t][2] = fmaf(xv.x, w0.z, fmaf(xv.y, w1.z, fmaf(xv.z, w2.z, fmaf(xv.w, w3.z, acc[t][2]))));
                acc[t][3] = fmaf(xv.x, w0.w, fmaf(xv.y, w1.w, fmaf(xv.z, w2.w, fmaf(xv.w, w3.w, acc[t][3]))));
            }
        }
        __syncthreads();
    }

    #pragma unroll
    for (int t = 0; t < 4; ++t) {
        int tok = ty * 4 + t;
        if (tok < nt) {
            int bg = pair_bg[start + tok];
            *(float4*)&y[(size_t)bg * D + ox * 4] =
                make_float4(acc[t][0], acc[t][1], acc[t][2], acc[t][3]);
        }
    }
}

// ---------------- combine: out[b] = lrelu(sum_g mask*y[b,g] / cnt) ----------------
__global__ __launch_bounds__(256) void moe_combine_kernel(
    const float* __restrict__ y, const int* __restrict__ genres,
    float* __restrict__ out)
{
    int gid = blockIdx.x * blockDim.x + threadIdx.x;  // over BATCH*32
    int b  = gid >> 5;
    int o4 = (gid & 31) * 4;

    int g0 = genres[b * NG + 0];
    int g1 = genres[b * NG + 1];
    int g2 = genres[b * NG + 2];

    float4 s = make_float4(0.f, 0.f, 0.f, 0.f);
    int cnt = 0;
    if (g0 != 0) { float4 v = *(const float4*)&y[((size_t)b * NG + 0) * D + o4]; s.x += v.x; s.y += v.y; s.z += v.z; s.w += v.w; ++cnt; }
    if (g1 != 0) { float4 v = *(const float4*)&y[((size_t)b * NG + 1) * D + o4]; s.x += v.x; s.y += v.y; s.z += v.z; s.w += v.w; ++cnt; }
    if (g2 != 0) { float4 v = *(const float4*)&y[((size_t)b * NG + 2) * D + o4]; s.x += v.x; s.y += v.y; s.z += v.z; s.w += v.w; ++cnt; }

    float inv = (cnt > 0) ? (1.0f / (float)cnt) : 0.0f;
    float4 r;
    r.x = s.x * inv; r.y = s.y * inv; r.z = s.z * inv; r.w = s.w * inv;
    r.x = (r.x >= 0.f) ? r.x : 0.01f * r.x;
    r.y = (r.y >= 0.f) ? r.y : 0.01f * r.y;
    r.z = (r.z >= 0.f) ? r.z : 0.01f * r.z;
    r.w = (r.w >= 0.f) ? r.w : 0.01f * r.w;
    *(float4*)&out[(size_t)b * D + o4] = r;
}

// ---------------- fallback (round-0 kernel) if ws is too small ----------------
__global__ __launch_bounds__(128) void moe_layer_kernel(
    const float* __restrict__ x, const int* __restrict__ genres,
    const float* __restrict__ W, float* __restrict__ out)
{
    const int b = blockIdx.x;
    const int o = threadIdx.x;
    __shared__ float xs[D];
    xs[o] = x[(size_t)b * D + o];
    __syncthreads();
    int e0 = genres[b * NG + 0], e1 = genres[b * NG + 1], e2 = genres[b * NG + 2];
    float acc = 0.0f; int cnt = 0;
    #pragma unroll
    for (int g = 0; g < NG; ++g) {
        int e = (g == 0) ? e0 : (g == 1) ? e1 : e2;
        if (e != 0) {
            ++cnt;
            const float* We = W + (size_t)e * D * D + o;
            float a = 0.0f;
            #pragma unroll 8
            for (int i = 0; i < D; ++i) a = fmaf(xs[i], We[(size_t)i * D], a);
            acc += a;
        }
    }
    float r = (cnt > 0) ? (acc / (float)cnt) : 0.0f;
    out[(size_t)b * D + o] = (r >= 0.0f) ? r : 0.01f * r;
}

extern "C" void kernel_launch(void* const* d_in, const int* in_sizes, int n_in,
                              void* d_out, int out_size, void* d_ws, size_t ws_size,
                              hipStream_t stream)
{
    const float* x      = (const float*)d_in[0];
    const int*   genres = (const int*)d_in[1];
    const float* W0     = (const float*)d_in[2];
    const float* W1     = (const float*)d_in[3];
    float*       out    = (float*)d_out;

    if (ws_size < WS_REQUIRED) {
        moe_layer_kernel<<<BATCH, D, 0, stream>>>(x,   genres, W0, out);
        moe_layer_kernel<<<BATCH, D, 0, stream>>>(out, genres, W1, out);
        return;
    }

    char* ws = (char*)d_ws;
    int*   ghist    = (int*)(ws + OFF_HIST);
    int*   gcur     = (int*)(ws + OFF_GCUR);
    int*   nTiles   = (int*)(ws + OFF_NT);
    int4*  tileInfo = (int4*)(ws + OFF_TILES);
    int*   pair_bg  = (int*)(ws + OFF_PAIR);
    float* y        = (float*)(ws + OFF_Y);
    float* tmp1     = (float*)(ws + OFF_TMP1);

    moe_init_kernel<<<1, NE, 0, stream>>>(ghist);
    moe_hist_kernel<<<NPAIR / 256, 256, 0, stream>>>(genres, ghist);
    moe_scan_tiles_kernel<<<1, 64, 0, stream>>>(ghist, gcur, nTiles, tileInfo);
    moe_scatter_kernel<<<NPAIR / 256, 256, 0, stream>>>(genres, gcur, pair_bg);

    moe_gemm_kernel<<<MAXT, 256, 0, stream>>>(x, W0, pair_bg, tileInfo, nTiles, y);
    moe_combine_kernel<<<(BATCH * 32) / 256, 256, 0, stream>>>(y, genres, tmp1);
    moe_gemm_kernel<<<MAXT, 256, 0, stream>>>(tmp1, W1, pair_bg, tileInfo, nTiles, y);
    moe_combine_kernel<<<(BATCH * 32) / 256, 256, 0, stream>>>(y, genres, out);
}

// Round 4
// 44.723 us; speedup vs baseline: 2.4067x; 1.3766x over previous
//
#include <hip/hip_runtime.h>

#define BATCH 8192
#define NG 3
#define NE 32
#define D 128
#define NPAIR (BATCH * NG)            // 24576
#define TILE 32                       // tokens per GEMM tile
#define MAXT (NPAIR / TILE + NE - 1)  // 799 worst-case tiles
#define NHB (NPAIR / 256)             // 96 hist blocks

typedef __attribute__((ext_vector_type(8))) short short8;
typedef __attribute__((ext_vector_type(4))) float f32x4;

// ---------------- workspace layout (bytes) ----------------
#define OFF_NT     0                      // int
#define OFF_TILES  256                    // int4[MAXT] = 12784
#define OFF_HISTPB 16384                  // int[96][32] = 12288
#define OFF_GCUR   28672                  // int[32]
#define OFF_PAIR   32768                  // int[NPAIR] = 98304
#define OFF_XB     131072                 // ushort[8192][128] = 2 MB
#define OFF_X1B    (OFF_XB  + (size_t)BATCH * D * 2)     // 2228224
#define OFF_WT0    (OFF_X1B + (size_t)BATCH * D * 2)     // 4325376
#define OFF_WT1    (OFF_WT0 + (size_t)NE * D * D * 2)    // 5373952
#define OFF_YB     (OFF_WT1 + (size_t)NE * D * D * 2)    // 6422528
#define WS_REQUIRED (OFF_YB + (size_t)NPAIR * D * 2)     // ~12.7 MB

static __device__ __forceinline__ ushort f2bf(float f) {
    unsigned b = __float_as_uint(f);
    unsigned r = (b + 0x7FFFu + ((b >> 16) & 1u)) >> 16;   // RNE
    return (ushort)r;
}
static __device__ __forceinline__ float bf2f(ushort u) {
    return __uint_as_float(((unsigned)u) << 16);
}

// ---------------- prep: x->bf16, W->Wt bf16 [e][col][k], per-block hist ----------------
__global__ __launch_bounds__(256) void moe_prep_kernel(
    const float* __restrict__ x, const float* __restrict__ W0,
    const float* __restrict__ W1, const int* __restrict__ genres,
    ushort* __restrict__ xb, ushort* __restrict__ Wt0,
    ushort* __restrict__ Wt1, int* __restrict__ ghist_pb)
{
    __shared__ ushort sT[128 * 132];
    __shared__ int sh[NE];
    const int bid = blockIdx.x, tid = threadIdx.x;

    if (bid < 512) {                       // x convert: 8 f32 -> 8 bf16 per thread
        size_t base = ((size_t)bid * 256 + tid) * 8;
        float4 f0 = *(const float4*)&x[base];
        float4 f1 = *(const float4*)&x[base + 4];
        ushort4 p0 = { f2bf(f0.x), f2bf(f0.y), f2bf(f0.z), f2bf(f0.w) };
        ushort4 p1 = { f2bf(f1.x), f2bf(f1.y), f2bf(f1.z), f2bf(f1.w) };
        *(ushort4*)&xb[base]     = p0;
        *(ushort4*)&xb[base + 4] = p1;
    } else if (bid < 576) {                // W transpose+convert, one expert per block
        const int wb = bid - 512;
        const float* Ws = ((wb < 32) ? W0 : W1) + (size_t)(wb & 31) * D * D;
        ushort* Wt = ((wb < 32) ? Wt0 : Wt1) + (size_t)(wb & 31) * D * D;
        #pragma unroll
        for (int i = 0; i < 16; ++i) {     // read [k][col] coalesced -> LDS bf16
            int f4 = tid + i * 256;
            int k = f4 >> 5, c4 = f4 & 31;
            float4 f = *(const float4*)&Ws[(size_t)k * D + c4 * 4];
            ushort4 p = { f2bf(f.x), f2bf(f.y), f2bf(f.z), f2bf(f.w) };
            *(ushort4*)&sT[k * 132 + c4 * 4] = p;
        }
        __syncthreads();
        #pragma unroll
        for (int i = 0; i < 8; ++i) {      // write [col][k] coalesced
            int f = tid + i * 256;
            int col = f >> 4, k0 = (f & 15) * 8;
            ushort u[8];
            #pragma unroll
            for (int j = 0; j < 8; ++j) u[j] = sT[(k0 + j) * 132 + col];
            ushort4 q0 = { u[0], u[1], u[2], u[3] };
            ushort4 q1 = { u[4], u[5], u[6], u[7] };
            *(ushort4*)&Wt[(size_t)col * D + k0]     = q0;
            *(ushort4*)&Wt[(size_t)col * D + k0 + 4] = q1;
        }
    } else {                               // histogram block
        const int h = bid - 576;
        if (tid < NE) sh[tid] = 0;
        __syncthreads();
        int g = genres[h * 256 + tid];
        if (g != 0) atomicAdd(&sh[g], 1);
        __syncthreads();
        if (tid < NE) ghist_pb[h * NE + tid] = sh[tid];
    }
}

// ---------------- scan: totals, offsets, tile list ----------------
__global__ void moe_scan_kernel(
    const int* __restrict__ ghist_pb, int* __restrict__ gcur,
    int* __restrict__ nTiles, int4* __restrict__ tileInfo)
{
    const int e = threadIdx.x;             // 64 threads
    int cnt = 0;
    if (e > 0 && e < NE)
        for (int h = 0; h < NHB; ++h) cnt += ghist_pb[h * NE + e];
    int ntl = (cnt + TILE - 1) / TILE;
    int off = 0, tbase = 0, ttot = 0;
    for (int j = 0; j < NE; ++j) {
        int cj = __shfl(cnt, j, 64);
        int tj = __shfl(ntl, j, 64);
        if (j < e) { off += cj; tbase += tj; }
        ttot += tj;
    }
    if (e < NE) gcur[e] = off;
    if (e == 0) *nTiles = ttot;
    for (int t = 0; t < ntl; ++t) {
        int rem = cnt - t * TILE;
        tileInfo[tbase + t] = make_int4(e, off + t * TILE, (rem < TILE) ? rem : TILE, 0);
    }
}

// ---------------- scatter: bucket pair ids by expert ----------------
// Within-bucket order is scheduling-dependent; every pair's y value depends
// only on (token, expert) with a fixed K-order, so outputs are invariant.
__global__ __launch_bounds__(256) void moe_scatter_kernel(
    const int* __restrict__ genres, int* __restrict__ gcur,
    int* __restrict__ pair_bg)
{
    __shared__ int shist[NE], sbase[NE], scur[NE];
    const int tid = threadIdx.x;
    if (tid < NE) { shist[tid] = 0; scur[tid] = 0; }
    __syncthreads();
    const int i = blockIdx.x * 256 + tid;
    const int g = genres[i];
    if (g != 0) atomicAdd(&shist[g], 1);
    __syncthreads();
    if (tid < NE && shist[tid] > 0) sbase[tid] = atomicAdd(&gcur[tid], shist[tid]);
    __syncthreads();
    if (g != 0) {
        int r = atomicAdd(&scur[g], 1);
        pair_bg[sbase[g] + r] = i;
    }
}

// ---------------- MFMA grouped GEMM: yb[pair][col] = x[tok] @ W[e] ----------------
// Tile: 32 tok x 128 col x K=128, fully staged. A = Wt (M=col), B = x (N=tok).
// 4 waves; wave w owns cols [32w,32w+32): 2x2 frags x 4 K-steps = 16 MFMA.
// LDS rows are 256 B -> XOR-swizzle byte ^ ((row&7)<<4) on both write & read.
__global__ __launch_bounds__(256) void moe_gemm_kernel(
    const ushort* __restrict__ xb,       // [BATCH][D] bf16
    const ushort* __restrict__ Wt,       // [NE][D col][D k] bf16
    const int* __restrict__ pair_bg,     // [NPAIR]
    const int4* __restrict__ tileInfo,   // [MAXT]
    const int* __restrict__ nTiles,
    ushort* __restrict__ yb)             // [NPAIR][D] bf16
{
    if ((int)blockIdx.x >= *nTiles) return;
    const int4 ti = tileInfo[blockIdx.x];
    const int e = ti.x, start = ti.y, nt = ti.z;

    __shared__ ushort sW[D * D];       // 32 KB
    __shared__ ushort sX[TILE * D];    // 8 KB
    __shared__ int sBG[TILE];

    const int tid = threadIdx.x;

    // stage W tile: contiguous copy, swizzled dest
    const uint4* wsrc = (const uint4*)(Wt + (size_t)e * D * D);
    #pragma unroll
    for (int i = 0; i < 8; ++i) {
        int c = tid + i * 256;
        int byteoff = (c * 16) ^ ((((c >> 4) & 7)) << 4);
        *(uint4*)((char*)sW + byteoff) = wsrc[c];
    }
    // stage x tile: 16 chunks (16 B) per token row
    #pragma unroll
    for (int i = 0; i < 2; ++i) {
        int c = tid + i * 256;
        int tok = c >> 4;
        int bg = pair_bg[start + ((tok < nt) ? tok : 0)];
        int row = bg / NG;
        const uint4* xs = (const uint4*)(xb + (size_t)row * D);
        int byteoff = (tok * 256 + (c & 15) * 16) ^ ((tok & 7) << 4);
        *(uint4*)((char*)sX + byteoff) = xs[c & 15];
    }
    if (tid < TILE) sBG[tid] = (tid < nt) ? pair_bg[start + tid] : 0;
    __syncthreads();

    const int wave = tid >> 6, lane = tid & 63;
    const int g = lane >> 4, l15 = lane & 15;

    f32x4 acc00 = {0.f,0.f,0.f,0.f}, acc01 = {0.f,0.f,0.f,0.f};
    f32x4 acc10 = {0.f,0.f,0.f,0.f}, acc11 = {0.f,0.f,0.f,0.f};

    #pragma unroll
    for (int ks = 0; ks < 4; ++ks) {
        const int kb = ks * 64 + g * 16;   // byte offset of k = 32ks + 8g
        int c0 = wave * 32 + l15;
        int c1 = c0 + 16;
        short8 a0 = *(const short8*)((const char*)sW + ((c0 * 256 + kb) ^ ((c0 & 7) << 4)));
        short8 a1 = *(const short8*)((const char*)sW + ((c1 * 256 + kb) ^ ((c1 & 7) << 4)));
        int t0 = l15, t1 = l15 + 16;
        short8 b0 = *(const short8*)((const char*)sX + ((t0 * 256 + kb) ^ ((t0 & 7) << 4)));
        short8 b1 = *(const short8*)((const char*)sX + ((t1 * 256 + kb) ^ ((t1 & 7) << 4)));
        acc00 = __builtin_amdgcn_mfma_f32_16x16x32_bf16(a0, b0, acc00, 0, 0, 0);
        acc01 = __builtin_amdgcn_mfma_f32_16x16x32_bf16(a0, b1, acc01, 0, 0, 0);
        acc10 = __builtin_amdgcn_mfma_f32_16x16x32_bf16(a1, b0, acc10, 0, 0, 0);
        acc11 = __builtin_amdgcn_mfma_f32_16x16x32_bf16(a1, b1, acc11, 0, 0, 0);
    }

    // epilogue: lane holds cols (wave*32 + m*16 + 4g + r) for tok = n*16 + l15
    #pragma unroll
    for (int n = 0; n < 2; ++n) {
        int tok = n * 16 + l15;
        if (tok < nt) {
            int bg = sBG[tok];
            ushort* dst = yb + (size_t)bg * D + wave * 32 + g * 4;
            f32x4 v0 = (n == 0) ? acc00 : acc01;
            f32x4 v1 = (n == 0) ? acc10 : acc11;
            ushort4 p0 = { f2bf(v0[0]), f2bf(v0[1]), f2bf(v0[2]), f2bf(v0[3]) };
            ushort4 p1 = { f2bf(v1[0]), f2bf(v1[1]), f2bf(v1[2]), f2bf(v1[3]) };
            *(ushort4*)(dst)      = p0;
            *(ushort4*)(dst + 16) = p1;
        }
    }
}

// ---------------- combine: avg over live slots + leaky relu ----------------
template<int OUT_F32>
__global__ __launch_bounds__(256) void moe_combine_kernel(
    const ushort* __restrict__ yb, const int* __restrict__ genres,
    void* __restrict__ outp)
{
    int gid = blockIdx.x * 256 + threadIdx.x;   // BATCH*16 chunks of 8
    int b = gid >> 4, c8 = (gid & 15) * 8;
    int g0 = genres[b * NG + 0];
    int g1 = genres[b * NG + 1];
    int g2 = genres[b * NG + 2];

    float s[8] = {0,0,0,0,0,0,0,0};
    int cnt = 0;
    #pragma unroll
    for (int slot = 0; slot < NG; ++slot) {
        int g = (slot == 0) ? g0 : (slot == 1) ? g1 : g2;
        if (g != 0) {
            ++cnt;
            uint4 v = *(const uint4*)&yb[((size_t)b * NG + slot) * D + c8];
            const unsigned w[4] = { v.x, v.y, v.z, v.w };
            #pragma unroll
            for (int j = 0; j < 4; ++j) {
                s[2*j]   += bf2f((ushort)(w[j] & 0xFFFF));
                s[2*j+1] += bf2f((ushort)(w[j] >> 16));
            }
        }
    }
    float fc = (cnt > 0) ? (float)cnt : 1.0f;
    float r[8];
    #pragma unroll
    for (int j = 0; j < 8; ++j) {
        float t = s[j] / fc;
        r[j] = (t >= 0.f) ? t : 0.01f * t;
    }
    if (OUT_F32) {
        float* out = (float*)outp;
        float4 lo = { r[0], r[1], r[2], r[3] };
        float4 hi = { r[4], r[5], r[6], r[7] };
        *(float4*)&out[(size_t)b * D + c8]     = lo;
        *(float4*)&out[(size_t)b * D + c8 + 4] = hi;
    } else {
        ushort* out = (ushort*)outp;
        ushort4 lo = { f2bf(r[0]), f2bf(r[1]), f2bf(r[2]), f2bf(r[3]) };
        ushort4 hi = { f2bf(r[4]), f2bf(r[5]), f2bf(r[6]), f2bf(r[7]) };
        *(ushort4*)&out[(size_t)b * D + c8]     = lo;
        *(ushort4*)&out[(size_t)b * D + c8 + 4] = hi;
    }
}

// ---------------- fallback (round-0 kernel) if ws is too small ----------------
__global__ __launch_bounds__(128) void moe_layer_kernel(
    const float* __restrict__ x, const int* __restrict__ genres,
    const float* __restrict__ W, float* __restrict__ out)
{
    const int b = blockIdx.x;
    const int o = threadIdx.x;
    __shared__ float xs[D];
    xs[o] = x[(size_t)b * D + o];
    __syncthreads();
    int e0 = genres[b * NG + 0], e1 = genres[b * NG + 1], e2 = genres[b * NG + 2];
    float acc = 0.0f; int cnt = 0;
    #pragma unroll
    for (int g = 0; g < NG; ++g) {
        int e = (g == 0) ? e0 : (g == 1) ? e1 : e2;
        if (e != 0) {
            ++cnt;
            const float* We = W + (size_t)e * D * D + o;
            float a = 0.0f;
            #pragma unroll 8
            for (int i = 0; i < D; ++i) a = fmaf(xs[i], We[(size_t)i * D], a);
            acc += a;
        }
    }
    float r = (cnt > 0) ? (acc / (float)cnt) : 0.0f;
    out[(size_t)b * D + o] = (r >= 0.0f) ? r : 0.01f * r;
}

extern "C" void kernel_launch(void* const* d_in, const int* in_sizes, int n_in,
                              void* d_out, int out_size, void* d_ws, size_t ws_size,
                              hipStream_t stream)
{
    const float* x      = (const float*)d_in[0];
    const int*   genres = (const int*)d_in[1];
    const float* W0     = (const float*)d_in[2];
    const float* W1     = (const float*)d_in[3];
    float*       out    = (float*)d_out;

    if (ws_size < WS_REQUIRED) {
        moe_layer_kernel<<<BATCH, D, 0, stream>>>(x,   genres, W0, out);
        moe_layer_kernel<<<BATCH, D, 0, stream>>>(out, genres, W1, out);
        return;
    }

    char* ws = (char*)d_ws;
    int*    nTiles   = (int*)(ws + OFF_NT);
    int4*   tileInfo = (int4*)(ws + OFF_TILES);
    int*    ghist_pb = (int*)(ws + OFF_HISTPB);
    int*    gcur     = (int*)(ws + OFF_GCUR);
    int*    pair_bg  = (int*)(ws + OFF_PAIR);
    ushort* xb       = (ushort*)(ws + OFF_XB);
    ushort* x1b      = (ushort*)(ws + OFF_X1B);
    ushort* Wt0      = (ushort*)(ws + OFF_WT0);
    ushort* Wt1      = (ushort*)(ws + OFF_WT1);
    ushort* yb       = (ushort*)(ws + OFF_YB);

    moe_prep_kernel<<<512 + 64 + NHB, 256, 0, stream>>>(x, W0, W1, genres,
                                                        xb, Wt0, Wt1, ghist_pb);
    moe_scan_kernel<<<1, 64, 0, stream>>>(ghist_pb, gcur, nTiles, tileInfo);
    moe_scatter_kernel<<<NHB, 256, 0, stream>>>(genres, gcur, pair_bg);

    moe_gemm_kernel<<<MAXT, 256, 0, stream>>>(xb, Wt0, pair_bg, tileInfo, nTiles, yb);
    moe_combine_kernel<0><<<BATCH * 16 / 256, 256, 0, stream>>>(yb, genres, (void*)x1b);
    moe_gemm_kernel<<<MAXT, 256, 0, stream>>>(x1b, Wt1, pair_bg, tileInfo, nTiles, yb);
    moe_combine_kernel<1><<<BATCH * 16 / 256, 256, 0, stream>>>(yb, genres, (void*)out);
}

// Round 5
// 42.380 us; speedup vs baseline: 2.5397x; 1.0553x over previous
//
#include <hip/hip_runtime.h>

#define BATCH 8192
#define NG 3
#define NE 32
#define D 128
#define NPAIR (BATCH * NG)            // 24576
#define TILE 32                       // tokens per GEMM tile
#define MAXT (NPAIR / TILE + NE - 1)  // 799 worst-case tiles
#define NHB (NPAIR / 256)             // 96 hist/scatter blocks

typedef __attribute__((ext_vector_type(8))) short short8;
typedef __attribute__((ext_vector_type(4))) float f32x4;

// ---------------- workspace layout (bytes) ----------------
#define OFF_NT     0                      // int
#define OFF_TILES  256                    // int4[MAXT] = 12784
#define OFF_HISTPB 16384                  // int[96][32] = 12288
#define OFF_PAIR   32768                  // int[NPAIR] = 98304
#define OFF_XB     131072                 // ushort[8192][128] = 2 MB
#define OFF_X1B    (OFF_XB  + (size_t)BATCH * D * 2)     // 2228224
#define OFF_WT0    (OFF_X1B + (size_t)BATCH * D * 2)     // 4325376
#define OFF_WT1    (OFF_WT0 + (size_t)NE * D * D * 2)    // 5373952
#define OFF_YB     (OFF_WT1 + (size_t)NE * D * D * 2)    // 6422528
#define WS_REQUIRED (OFF_YB + (size_t)NPAIR * D * 2)     // ~12.7 MB

static __device__ __forceinline__ ushort f2bf(float f) {
    unsigned b = __float_as_uint(f);
    unsigned r = (b + 0x7FFFu + ((b >> 16) & 1u)) >> 16;   // RNE
    return (ushort)r;
}
static __device__ __forceinline__ float bf2f(ushort u) {
    return __uint_as_float(((unsigned)u) << 16);
}

// global -> LDS direct copy, 16 B per lane. LDS base must be wave-uniform;
// HW writes ldsbase + lane*16. Global ptr is per-lane.
static __device__ __forceinline__ void gl_lds16(const void* g, void* l) {
    __builtin_amdgcn_global_load_lds(
        (const __attribute__((address_space(1))) void*)g,
        (__attribute__((address_space(3))) void*)l, 16, 0, 0);
}

// ---------------- prep: x->bf16 | W->Wt bf16 SWIZZLED | per-block hist ----------------
// Wt global layout per expert: byte (col*256 + k*2) ^ ((col&7)<<4) holds
// W^T[col][k] bf16 -> GEMM stages it with a pure linear global_load_lds copy
// and reads A-fragments with the same XOR (T2 swizzle, bank-conflict-free).
__global__ __launch_bounds__(256) void moe_prep_kernel(
    const float* __restrict__ x, const float* __restrict__ W0,
    const float* __restrict__ W1, const int* __restrict__ genres,
    ushort* __restrict__ xb, ushort* __restrict__ Wt0,
    ushort* __restrict__ Wt1, int* __restrict__ hist_pb)
{
    __shared__ ushort sT[128 * 68];   // padded: byte stride 136 (8B-aligned, bank+2)
    __shared__ int sh[NE];
    const int bid = blockIdx.x, tid = threadIdx.x;

    if (bid < 512) {                       // x convert: 8 f32 -> 8 bf16 per thread
        size_t base = ((size_t)bid * 256 + tid) * 8;
        float4 f0 = *(const float4*)&x[base];
        float4 f1 = *(const float4*)&x[base + 4];
        ushort4 p0 = { f2bf(f0.x), f2bf(f0.y), f2bf(f0.z), f2bf(f0.w) };
        ushort4 p1 = { f2bf(f1.x), f2bf(f1.y), f2bf(f1.z), f2bf(f1.w) };
        *(ushort4*)&xb[base]     = p0;
        *(ushort4*)&xb[base + 4] = p1;
    } else if (bid < 640) {                // W transpose: 2 blocks per matrix (64 cols)
        const int wb = bid - 512;          // 0..127
        const int m = wb >> 1;             // matrix 0..63
        const int hcol = wb & 1;           // column half
        const float* Ws = ((m < 32) ? W0 : W1) + (size_t)(m & 31) * D * D;
        ushort* Wte = ((m < 32) ? Wt0 : Wt1) + (size_t)(m & 31) * D * D;

        #pragma unroll
        for (int i = 0; i < 8; ++i) {      // read [k][col-half] coalesced -> LDS bf16
            int f4 = tid + i * 256;        // 0..2047
            int k = f4 >> 4, c4 = f4 & 15;
            float4 f = *(const float4*)&Ws[(size_t)k * D + hcol * 64 + c4 * 4];
            ushort4 p = { f2bf(f.x), f2bf(f.y), f2bf(f.z), f2bf(f.w) };
            *(ushort4*)&sT[k * 68 + c4 * 4] = p;
        }
        __syncthreads();
        #pragma unroll
        for (int i = 0; i < 4; ++i) {      // write [col][k], swizzled dest
            int f = tid + i * 256;         // 0..1023
            int cl = f >> 4, k0 = (f & 15) * 8;
            int col = hcol * 64 + cl;
            ushort u[8];
            #pragma unroll
            for (int j = 0; j < 8; ++j) u[j] = sT[(k0 + j) * 68 + cl];
            ushort4 q0 = { u[0], u[1], u[2], u[3] };
            ushort4 q1 = { u[4], u[5], u[6], u[7] };
            int byteoff = (col * 256 + k0 * 2) ^ ((col & 7) << 4);
            *(ushort4*)((char*)Wte + byteoff)     = q0;
            *(ushort4*)((char*)Wte + byteoff + 8) = q1;
        }
    } else {                               // histogram block
        const int h = bid - 640;
        if (tid < NE) sh[tid] = 0;
        __syncthreads();
        int g = genres[h * 256 + tid];
        if (g != 0) atomicAdd(&sh[g], 1);
        __syncthreads();
        if (tid < NE) hist_pb[h * NE + tid] = sh[tid];
    }
}

// ---------------- scatter (+ fused scan/tile-build in block 0) ----------------
// Each block computes its own bucket bases from the per-block hist table:
// base[p][e] = sum_{e'<e} total[e'] + sum_{h<p} hist[h][e]. No global scan
// kernel, no global atomics. Within-block rank via LDS atomics is
// scheduling-ordered, but y is indexed by pair id -> output invariant.
__global__ __launch_bounds__(256) void moe_scatter_kernel(
    const int* __restrict__ genres, const int* __restrict__ hist_pb,
    int* __restrict__ pair_bg, int* __restrict__ nTiles,
    int4* __restrict__ tileInfo)
{
    __shared__ int sbase[NE], scur[NE];
    const int p = blockIdx.x, tid = threadIdx.x;

    if (tid < NE) {
        int tot = 0, pre = 0;
        for (int h = 0; h < NHB; ++h) {
            int c = hist_pb[h * NE + tid];
            tot += c;
            if (h < p) pre += c;
        }
        int off = 0;
        for (int j = 0; j < NE; ++j) {
            int tj = __shfl(tot, j, 64);
            if (j < tid) off += tj;
        }
        sbase[tid] = off + pre;
        scur[tid] = 0;
        if (p == 0) {                      // block 0 also emits the tile list
            int ntl = (tot + TILE - 1) / TILE;
            int tbase = 0, ttot = 0;
            for (int j = 0; j < NE; ++j) {
                int nj = __shfl(ntl, j, 64);
                if (j < tid) tbase += nj;
                ttot += nj;
            }
            if (tid == 0) *nTiles = ttot;
            for (int t = 0; t < ntl; ++t) {
                int rem = tot - t * TILE;
                tileInfo[tbase + t] =
                    make_int4(tid, off + t * TILE, (rem < TILE) ? rem : TILE, 0);
            }
        }
    }
    __syncthreads();
    const int i = p * 256 + tid;
    const int g = genres[i];
    if (g != 0) {
        int r = atomicAdd(&scur[g], 1);
        pair_bg[sbase[g] + r] = i;
    }
}

// ---------------- MFMA grouped GEMM: yb[pair][col] = x[tok] @ W[e] ----------------
// Tile: 32 tok x 128 col x K=128 fully staged via global_load_lds (16B):
// sW = linear copy of pre-swizzled Wt tile; sX = linear LDS dest with
// pre-swizzled per-lane global chunk addresses (m173 pattern).
// 4 waves x 16 mfma_f32_16x16x32_bf16. LDS 40 KB -> 4 blocks/CU.
__global__ __launch_bounds__(256, 4) void moe_gemm_kernel(
    const ushort* __restrict__ xb,       // [BATCH][D] bf16
    const ushort* __restrict__ Wt,       // [NE] swizzled [col][k] bf16
    const int* __restrict__ pair_bg,     // [NPAIR]
    const int4* __restrict__ tileInfo,   // [MAXT]
    const int* __restrict__ nTiles,
    ushort* __restrict__ yb)             // [NPAIR][D] bf16
{
    if ((int)blockIdx.x >= *nTiles) return;
    const int4 ti = tileInfo[blockIdx.x];
    const int e = ti.x, start = ti.y, nt = ti.z;

    __shared__ ushort sW[D * D];       // 32768 B
    __shared__ ushort sX[TILE * D];    // 8192 B

    const int tid = threadIdx.x;
    const int wave = tid >> 6, lane = tid & 63;
    char* sWb = (char*)sW;
    char* sXb = (char*)sX;

    // stage W: linear 1KB-per-instruction DMA of the pre-swizzled tile
    const char* wsrc = (const char*)(Wt + (size_t)e * D * D);
    #pragma unroll
    for (int i = 0; i < 8; ++i) {
        int chunk = wave * 8 + i;                       // 0..31
        gl_lds16(wsrc + chunk * 1024 + lane * 16, sWb + chunk * 1024);
    }
    // stage x: 4 tokens per 1KB chunk; swizzle via source chunk permutation
    #pragma unroll
    for (int i = 0; i < 2; ++i) {
        int chunk = wave * 2 + i;                       // 0..7
        int tok = chunk * 4 + (lane >> 4);              // 0..31
        int ch  = lane & 15;
        int bg = pair_bg[start + ((tok < nt) ? tok : 0)];
        int row = bg / NG;
        const char* src = (const char*)(xb + (size_t)row * D)
                        + ((ch * 16) ^ ((tok & 7) << 4));
        gl_lds16(src, sXb + chunk * 1024);
    }
    __syncthreads();   // emits s_waitcnt vmcnt(0) + barrier

    const int g = lane >> 4, l15 = lane & 15;

    f32x4 acc00 = {0.f,0.f,0.f,0.f}, acc01 = {0.f,0.f,0.f,0.f};
    f32x4 acc10 = {0.f,0.f,0.f,0.f}, acc11 = {0.f,0.f,0.f,0.f};

    #pragma unroll
    for (int ks = 0; ks < 4; ++ks) {
        const int kb = ks * 64 + g * 16;   // byte offset of k = 32ks + 8g
        int c0 = wave * 32 + l15;
        int c1 = c0 + 16;
        short8 a0 = *(const short8*)(sWb + ((c0 * 256 + kb) ^ ((c0 & 7) << 4)));
        short8 a1 = *(const short8*)(sWb + ((c1 * 256 + kb) ^ ((c1 & 7) << 4)));
        int t0 = l15, t1 = l15 + 16;
        short8 b0 = *(const short8*)(sXb + ((t0 * 256 + kb) ^ ((t0 & 7) << 4)));
        short8 b1 = *(const short8*)(sXb + ((t1 * 256 + kb) ^ ((t1 & 7) << 4)));
        acc00 = __builtin_amdgcn_mfma_f32_16x16x32_bf16(a0, b0, acc00, 0, 0, 0);
        acc01 = __builtin_amdgcn_mfma_f32_16x16x32_bf16(a0, b1, acc01, 0, 0, 0);
        acc10 = __builtin_amdgcn_mfma_f32_16x16x32_bf16(a1, b0, acc10, 0, 0, 0);
        acc11 = __builtin_amdgcn_mfma_f32_16x16x32_bf16(a1, b1, acc11, 0, 0, 0);
    }

    // epilogue: lane holds cols (wave*32 + m*16 + 4g + r) for tok = n*16 + l15
    #pragma unroll
    for (int n = 0; n < 2; ++n) {
        int tok = n * 16 + l15;
        if (tok < nt) {
            int bg = pair_bg[start + tok];              // L1-hot broadcast
            ushort* dst = yb + (size_t)bg * D + wave * 32 + g * 4;
            f32x4 v0 = (n == 0) ? acc00 : acc01;
            f32x4 v1 = (n == 0) ? acc10 : acc11;
            ushort4 p0 = { f2bf(v0[0]), f2bf(v0[1]), f2bf(v0[2]), f2bf(v0[3]) };
            ushort4 p1 = { f2bf(v1[0]), f2bf(v1[1]), f2bf(v1[2]), f2bf(v1[3]) };
            *(ushort4*)(dst)      = p0;
            *(ushort4*)(dst + 16) = p1;
        }
    }
}

// ---------------- combine: avg over live slots + leaky relu ----------------
template<int OUT_F32>
__global__ __launch_bounds__(256) void moe_combine_kernel(
    const ushort* __restrict__ yb, const int* __restrict__ genres,
    void* __restrict__ outp)
{
    int gid = blockIdx.x * 256 + threadIdx.x;   // BATCH*16 chunks of 8
    int b = gid >> 4, c8 = (gid & 15) * 8;
    int g0 = genres[b * NG + 0];
    int g1 = genres[b * NG + 1];
    int g2 = genres[b * NG + 2];

    float s[8] = {0,0,0,0,0,0,0,0};
    int cnt = 0;
    #pragma unroll
    for (int slot = 0; slot < NG; ++slot) {
        int g = (slot == 0) ? g0 : (slot == 1) ? g1 : g2;
        if (g != 0) {
            ++cnt;
            uint4 v = *(const uint4*)&yb[((size_t)b * NG + slot) * D + c8];
            const unsigned w[4] = { v.x, v.y, v.z, v.w };
            #pragma unroll
            for (int j = 0; j < 4; ++j) {
                s[2*j]   += bf2f((ushort)(w[j] & 0xFFFF));
                s[2*j+1] += bf2f((ushort)(w[j] >> 16));
            }
        }
    }
    float fc = (cnt > 0) ? (float)cnt : 1.0f;
    float r[8];
    #pragma unroll
    for (int j = 0; j < 8; ++j) {
        float t = s[j] / fc;
        r[j] = (t >= 0.f) ? t : 0.01f * t;
    }
    if (OUT_F32) {
        float* out = (float*)outp;
        float4 lo = { r[0], r[1], r[2], r[3] };
        float4 hi = { r[4], r[5], r[6], r[7] };
        *(float4*)&out[(size_t)b * D + c8]     = lo;
        *(float4*)&out[(size_t)b * D + c8 + 4] = hi;
    } else {
        ushort* out = (ushort*)outp;
        ushort4 lo = { f2bf(r[0]), f2bf(r[1]), f2bf(r[2]), f2bf(r[3]) };
        ushort4 hi = { f2bf(r[4]), f2bf(r[5]), f2bf(r[6]), f2bf(r[7]) };
        *(ushort4*)&out[(size_t)b * D + c8]     = lo;
        *(ushort4*)&out[(size_t)b * D + c8 + 4] = hi;
    }
}

// ---------------- fallback (round-0 kernel) if ws is too small ----------------
__global__ __launch_bounds__(128) void moe_layer_kernel(
    const float* __restrict__ x, const int* __restrict__ genres,
    const float* __restrict__ W, float* __restrict__ out)
{
    const int b = blockIdx.x;
    const int o = threadIdx.x;
    __shared__ float xs[D];
    xs[o] = x[(size_t)b * D + o];
    __syncthreads();
    int e0 = genres[b * NG + 0], e1 = genres[b * NG + 1], e2 = genres[b * NG + 2];
    float acc = 0.0f; int cnt = 0;
    #pragma unroll
    for (int g = 0; g < NG; ++g) {
        int e = (g == 0) ? e0 : (g == 1) ? e1 : e2;
        if (e != 0) {
            ++cnt;
            const float* We = W + (size_t)e * D * D + o;
            float a = 0.0f;
            #pragma unroll 8
            for (int i = 0; i < D; ++i) a = fmaf(xs[i], We[(size_t)i * D], a);
            acc += a;
        }
    }
    float r = (cnt > 0) ? (acc / (float)cnt) : 0.0f;
    out[(size_t)b * D + o] = (r >= 0.0f) ? r : 0.01f * r;
}

extern "C" void kernel_launch(void* const* d_in, const int* in_sizes, int n_in,
                              void* d_out, int out_size, void* d_ws, size_t ws_size,
                              hipStream_t stream)
{
    const float* x      = (const float*)d_in[0];
    const int*   genres = (const int*)d_in[1];
    const float* W0     = (const float*)d_in[2];
    const float* W1     = (const float*)d_in[3];
    float*       out    = (float*)d_out;

    if (ws_size < WS_REQUIRED) {
        moe_layer_kernel<<<BATCH, D, 0, stream>>>(x,   genres, W0, out);
        moe_layer_kernel<<<BATCH, D, 0, stream>>>(out, genres, W1, out);
        return;
    }

    char* ws = (char*)d_ws;
    int*    nTiles   = (int*)(ws + OFF_NT);
    int4*   tileInfo = (int4*)(ws + OFF_TILES);
    int*    hist_pb  = (int*)(ws + OFF_HISTPB);
    int*    pair_bg  = (int*)(ws + OFF_PAIR);
    ushort* xb       = (ushort*)(ws + OFF_XB);
    ushort* x1b      = (ushort*)(ws + OFF_X1B);
    ushort* Wt0      = (ushort*)(ws + OFF_WT0);
    ushort* Wt1      = (ushort*)(ws + OFF_WT1);
    ushort* yb       = (ushort*)(ws + OFF_YB);

    moe_prep_kernel<<<512 + 128 + NHB, 256, 0, stream>>>(x, W0, W1, genres,
                                                         xb, Wt0, Wt1, hist_pb);
    moe_scatter_kernel<<<NHB, 256, 0, stream>>>(genres, hist_pb, pair_bg,
                                                nTiles, tileInfo);

    moe_gemm_kernel<<<MAXT, 256, 0, stream>>>(xb, Wt0, pair_bg, tileInfo, nTiles, yb);
    moe_combine_kernel<0><<<BATCH * 16 / 256, 256, 0, stream>>>(yb, genres, (void*)x1b);
    moe_gemm_kernel<<<MAXT, 256, 0, stream>>>(x1b, Wt1, pair_bg, tileInfo, nTiles, yb);
    moe_combine_kernel<1><<<BATCH * 16 / 256, 256, 0, stream>>>(yb, genres, (void*)out);
}

// Round 6
// 36.920 us; speedup vs baseline: 2.9153x; 1.1479x over previous
//
#include <hip/hip_runtime.h>

#define BATCH 8192
#define NG 3
#define NE 32
#define D 128
#define NPAIR (BATCH * NG)            // 24576
#define TILE 32                       // tokens per GEMM tile
#define MAXT (NPAIR / TILE + NE - 1)  // 799 worst-case tiles
#define NHB (NPAIR / 256)             // 96 hist/scatter blocks

typedef __attribute__((ext_vector_type(8))) short short8;
typedef __attribute__((ext_vector_type(4))) float f32x4;

// ---------------- workspace layout (bytes) ----------------
#define OFF_NT     0                      // int
#define OFF_TILES  256                    // int4[MAXT] = 12784
#define OFF_HISTPB 16384                  // int[96][32] = 12288
#define OFF_PAIR   32768                  // int[NPAIR] = 98304 -> ends 131072
#define OFF_WT0    131072                 // swizzled bf16 W0^T, 1 MB
#define OFF_WT1    (OFF_WT0 + (size_t)NE * D * D * 2)
#define OFF_YB     (OFF_WT1 + (size_t)NE * D * D * 2)    // bf16 [NPAIR][D], 6 MB
#define OFF_YB2    (OFF_YB  + (size_t)NPAIR * D * 2)     // bf16 [NPAIR][D], 6 MB
#define WS_REQUIRED (OFF_YB2 + (size_t)NPAIR * D * 2)    // ~14.8 MB

static __device__ __forceinline__ ushort f2bf(float f) {
    unsigned b = __float_as_uint(f);
    unsigned r = (b + 0x7FFFu + ((b >> 16) & 1u)) >> 16;   // RNE
    return (ushort)r;
}
static __device__ __forceinline__ float bf2f(ushort u) {
    return __uint_as_float(((unsigned)u) << 16);
}
static __device__ __forceinline__ unsigned pk2(float lo, float hi) {
    return (unsigned)f2bf(lo) | ((unsigned)f2bf(hi) << 16);
}

// global -> LDS direct copy, 16 B per lane. LDS base wave-uniform; HW writes
// ldsbase + lane*16. Global ptr is per-lane.
static __device__ __forceinline__ void gl_lds16(const void* g, void* l) {
    __builtin_amdgcn_global_load_lds(
        (const __attribute__((address_space(1))) void*)g,
        (__attribute__((address_space(3))) void*)l, 16, 0, 0);
}

// ---------------- prep: W->Wt bf16 SWIZZLED | per-block hist ----------------
// Wt global layout per expert: byte (col*256 + k*2) ^ ((col&7)<<4) holds
// W^T[col][k] bf16 -> GEMM stages it with a pure linear global_load_lds copy
// and reads A-fragments with the same XOR (T2 swizzle, conflict-free).
__global__ __launch_bounds__(256) void moe_prep_kernel(
    const float* __restrict__ W0, const float* __restrict__ W1,
    const int* __restrict__ genres, ushort* __restrict__ Wt0,
    ushort* __restrict__ Wt1, int* __restrict__ hist_pb)
{
    __shared__ ushort sT[128 * 68];   // byte stride 136: 8B-aligned, bank-staggered
    __shared__ int sh[NE];
    const int bid = blockIdx.x, tid = threadIdx.x;

    if (bid < 128) {                       // W transpose: 2 blocks per matrix (64 cols)
        const int m = bid >> 1;            // matrix 0..63
        const int hcol = bid & 1;          // column half
        const float* Ws = ((m < 32) ? W0 : W1) + (size_t)(m & 31) * D * D;
        ushort* Wte = ((m < 32) ? Wt0 : Wt1) + (size_t)(m & 31) * D * D;

        #pragma unroll
        for (int i = 0; i < 8; ++i) {      // read [k][col-half] coalesced -> LDS bf16
            int f4 = tid + i * 256;        // 0..2047
            int k = f4 >> 4, c4 = f4 & 15;
            float4 f = *(const float4*)&Ws[(size_t)k * D + hcol * 64 + c4 * 4];
            ushort4 p = { f2bf(f.x), f2bf(f.y), f2bf(f.z), f2bf(f.w) };
            *(ushort4*)&sT[k * 68 + c4 * 4] = p;
        }
        __syncthreads();
        #pragma unroll
        for (int i = 0; i < 4; ++i) {      // write [col][k], swizzled dest
            int f = tid + i * 256;         // 0..1023
            int cl = f >> 4, k0 = (f & 15) * 8;
            int col = hcol * 64 + cl;
            ushort u[8];
            #pragma unroll
            for (int j = 0; j < 8; ++j) u[j] = sT[(k0 + j) * 68 + cl];
            ushort4 q0 = { u[0], u[1], u[2], u[3] };
            ushort4 q1 = { u[4], u[5], u[6], u[7] };
            int byteoff = (col * 256 + k0 * 2) ^ ((col & 7) << 4);
            *(ushort4*)((char*)Wte + byteoff)     = q0;
            *(ushort4*)((char*)Wte + byteoff + 8) = q1;
        }
    } else {                               // histogram block
        const int h = bid - 128;
        if (tid < NE) sh[tid] = 0;
        __syncthreads();
        int g = genres[h * 256 + tid];
        if (g != 0) atomicAdd(&sh[g], 1);
        __syncthreads();
        if (tid < NE) hist_pb[h * NE + tid] = sh[tid];
    }
}

// ---------------- scatter (+ fused scan/tile-build in block 0) ----------------
// Each block derives its bucket bases from the per-block hist table; no global
// scan kernel, no global atomics. Within-block rank order is scheduling-
// dependent, but y is indexed by pair id -> output invariant.
__global__ __launch_bounds__(256) void moe_scatter_kernel(
    const int* __restrict__ genres, const int* __restrict__ hist_pb,
    int* __restrict__ pair_bg, int* __restrict__ nTiles,
    int4* __restrict__ tileInfo)
{
    __shared__ int sbase[NE], scur[NE];
    const int p = blockIdx.x, tid = threadIdx.x;

    if (tid < NE) {
        int tot = 0, pre = 0;
        for (int h = 0; h < NHB; ++h) {
            int c = hist_pb[h * NE + tid];
            tot += c;
            if (h < p) pre += c;
        }
        int off = 0;
        for (int j = 0; j < NE; ++j) {
            int tj = __shfl(tot, j, 64);
            if (j < tid) off += tj;
        }
        sbase[tid] = off + pre;
        scur[tid] = 0;
        if (p == 0) {                      // block 0 also emits the tile list
            int ntl = (tot + TILE - 1) / TILE;
            int tbase = 0, ttot = 0;
            for (int j = 0; j < NE; ++j) {
                int nj = __shfl(ntl, j, 64);
                if (j < tid) tbase += nj;
                ttot += nj;
            }
            if (tid == 0) *nTiles = ttot;
            for (int t = 0; t < ntl; ++t) {
                int rem = tot - t * TILE;
                tileInfo[tbase + t] =
                    make_int4(tid, off + t * TILE, (rem < TILE) ? rem : TILE, 0);
            }
        }
    }
    __syncthreads();
    const int i = p * 256 + tid;
    const int g = genres[i];
    if (g != 0) {
        int r = atomicAdd(&scur[g], 1);
        pair_bg[sbase[g] + r] = i;
    }
}

// ---------------- GEMM layer 1: yb[pair] = (x[tok]/cnt) @ W[e] ----------------
// sW: linear 16B DMA of pre-swizzled Wt tile. sX: reg-staged from f32 x with
// fused bf16 convert + 1/cnt scale, swizzled ds_write. 4 waves x 16 MFMA.
__global__ __launch_bounds__(256, 4) void moe_gemm1_kernel(
    const float* __restrict__ x, const int* __restrict__ genres,
    const ushort* __restrict__ Wt, const int* __restrict__ pair_bg,
    const int4* __restrict__ tileInfo, const int* __restrict__ nTiles,
    ushort* __restrict__ yb)
{
    if ((int)blockIdx.x >= *nTiles) return;
    const int4 ti = tileInfo[blockIdx.x];
    const int e = ti.x, start = ti.y, nt = ti.z;

    __shared__ ushort sW[D * D];       // 32768 B
    __shared__ ushort sX[TILE * D];    // 8192 B

    const int tid = threadIdx.x;
    const int wave = tid >> 6, lane = tid & 63;
    char* sWb = (char*)sW;
    char* sXb = (char*)sX;

    // stage W first: linear DMA, no dependencies
    const char* wsrc = (const char*)(Wt + (size_t)e * D * D);
    #pragma unroll
    for (int i = 0; i < 8; ++i) {
        int c = wave * 8 + i;
        gl_lds16(wsrc + c * 1024 + lane * 16, sWb + c * 1024);
    }

    // stage x: 8 threads per token, 16 f32 each; convert+scale in regs
    {
        const int t = tid >> 3, th = tid & 7;
        int bg = pair_bg[start + ((t < nt) ? t : 0)];
        int row = bg / NG;
        int g0 = genres[row * NG + 0];
        int g1 = genres[row * NG + 1];
        int g2 = genres[row * NG + 2];
        int cnt = (g0 != 0) + (g1 != 0) + (g2 != 0);
        float scale = 1.0f / (float)((cnt > 0) ? cnt : 1);
        const float* xp = x + (size_t)row * D + th * 16;
        float v[16];
        *(float4*)&v[0]  = *(const float4*)(xp);
        *(float4*)&v[4]  = *(const float4*)(xp + 4);
        *(float4*)&v[8]  = *(const float4*)(xp + 8);
        *(float4*)&v[12] = *(const float4*)(xp + 12);
        unsigned q[8];
        #pragma unroll
        for (int j = 0; j < 8; ++j) q[j] = pk2(v[2*j] * scale, v[2*j+1] * scale);
        int b0 = (t * 256 + (th * 2) * 16)     ^ ((t & 7) << 4);
        int b1 = (t * 256 + (th * 2 + 1) * 16) ^ ((t & 7) << 4);
        *(uint4*)(sXb + b0) = make_uint4(q[0], q[1], q[2], q[3]);
        *(uint4*)(sXb + b1) = make_uint4(q[4], q[5], q[6], q[7]);
    }
    __syncthreads();

    const int g = lane >> 4, l15 = lane & 15;
    f32x4 acc00 = {0.f,0.f,0.f,0.f}, acc01 = {0.f,0.f,0.f,0.f};
    f32x4 acc10 = {0.f,0.f,0.f,0.f}, acc11 = {0.f,0.f,0.f,0.f};

    #pragma unroll
    for (int ks = 0; ks < 4; ++ks) {
        const int kb = ks * 64 + g * 16;
        int c0 = wave * 32 + l15, c1 = c0 + 16;
        short8 a0 = *(const short8*)(sWb + ((c0 * 256 + kb) ^ ((c0 & 7) << 4)));
        short8 a1 = *(const short8*)(sWb + ((c1 * 256 + kb) ^ ((c1 & 7) << 4)));
        int t0 = l15, t1 = l15 + 16;
        short8 b0 = *(const short8*)(sXb + ((t0 * 256 + kb) ^ ((t0 & 7) << 4)));
        short8 b1 = *(const short8*)(sXb + ((t1 * 256 + kb) ^ ((t1 & 7) << 4)));
        acc00 = __builtin_amdgcn_mfma_f32_16x16x32_bf16(a0, b0, acc00, 0, 0, 0);
        acc01 = __builtin_amdgcn_mfma_f32_16x16x32_bf16(a0, b1, acc01, 0, 0, 0);
        acc10 = __builtin_amdgcn_mfma_f32_16x16x32_bf16(a1, b0, acc10, 0, 0, 0);
        acc11 = __builtin_amdgcn_mfma_f32_16x16x32_bf16(a1, b1, acc11, 0, 0, 0);
    }

    #pragma unroll
    for (int n = 0; n < 2; ++n) {
        int tok = n * 16 + l15;
        if (tok < nt) {
            int bg = pair_bg[start + tok];
            ushort* dst = yb + (size_t)bg * D + wave * 32 + g * 4;
            f32x4 v0 = (n == 0) ? acc00 : acc01;
            f32x4 v1 = (n == 0) ? acc10 : acc11;
            ushort4 p0 = { f2bf(v0[0]), f2bf(v0[1]), f2bf(v0[2]), f2bf(v0[3]) };
            ushort4 p1 = { f2bf(v1[0]), f2bf(v1[1]), f2bf(v1[2]), f2bf(v1[3]) };
            *(ushort4*)(dst)      = p0;
            *(ushort4*)(dst + 16) = p1;
        }
    }
}

// ---------------- GEMM layer 2 (fused layer-1 combine in staging) ----------------
// staged x1 = bf16( lrelu( sum_live_slots yb[tok,slot] ) / cnt ); then
// yb2[pair] = x1 @ W1[e].
__global__ __launch_bounds__(256, 4) void moe_gemm2_kernel(
    const ushort* __restrict__ yb, const int* __restrict__ genres,
    const ushort* __restrict__ Wt, const int* __restrict__ pair_bg,
    const int4* __restrict__ tileInfo, const int* __restrict__ nTiles,
    ushort* __restrict__ yb2)
{
    if ((int)blockIdx.x >= *nTiles) return;
    const int4 ti = tileInfo[blockIdx.x];
    const int e = ti.x, start = ti.y, nt = ti.z;

    __shared__ ushort sW[D * D];
    __shared__ ushort sX[TILE * D];

    const int tid = threadIdx.x;
    const int wave = tid >> 6, lane = tid & 63;
    char* sWb = (char*)sW;
    char* sXb = (char*)sX;

    const char* wsrc = (const char*)(Wt + (size_t)e * D * D);
    #pragma unroll
    for (int i = 0; i < 8; ++i) {
        int c = wave * 8 + i;
        gl_lds16(wsrc + c * 1024 + lane * 16, sWb + c * 1024);
    }

    // stage x1: 8 threads per token, 16 cols each; fused combine+lrelu+scale
    {
        const int t = tid >> 3, th = tid & 7;
        int bg = pair_bg[start + ((t < nt) ? t : 0)];
        int row = bg / NG;
        int g0 = genres[row * NG + 0];
        int g1 = genres[row * NG + 1];
        int g2 = genres[row * NG + 2];
        int cnt = (g0 != 0) + (g1 != 0) + (g2 != 0);
        float scale = 1.0f / (float)((cnt > 0) ? cnt : 1);

        float s[16];
        #pragma unroll
        for (int j = 0; j < 16; ++j) s[j] = 0.0f;
        #pragma unroll
        for (int slot = 0; slot < NG; ++slot) {
            int gg = (slot == 0) ? g0 : (slot == 1) ? g1 : g2;
            if (gg != 0) {
                const ushort* yp = yb + ((size_t)row * NG + slot) * D + th * 16;
                uint4 va = *(const uint4*)yp;
                uint4 vb = *(const uint4*)(yp + 8);
                unsigned w[8] = { va.x, va.y, va.z, va.w, vb.x, vb.y, vb.z, vb.w };
                #pragma unroll
                for (int j = 0; j < 8; ++j) {
                    s[2*j]   += bf2f((ushort)(w[j] & 0xFFFF));
                    s[2*j+1] += bf2f((ushort)(w[j] >> 16));
                }
            }
        }
        unsigned q[8];
        #pragma unroll
        for (int j = 0; j < 8; ++j) {
            float lo = s[2*j],  hi = s[2*j+1];
            lo = ((lo >= 0.f) ? lo : 0.01f * lo) * scale;
            hi = ((hi >= 0.f) ? hi : 0.01f * hi) * scale;
            q[j] = pk2(lo, hi);
        }
        int b0 = (t * 256 + (th * 2) * 16)     ^ ((t & 7) << 4);
        int b1 = (t * 256 + (th * 2 + 1) * 16) ^ ((t & 7) << 4);
        *(uint4*)(sXb + b0) = make_uint4(q[0], q[1], q[2], q[3]);
        *(uint4*)(sXb + b1) = make_uint4(q[4], q[5], q[6], q[7]);
    }
    __syncthreads();

    const int g = lane >> 4, l15 = lane & 15;
    f32x4 acc00 = {0.f,0.f,0.f,0.f}, acc01 = {0.f,0.f,0.f,0.f};
    f32x4 acc10 = {0.f,0.f,0.f,0.f}, acc11 = {0.f,0.f,0.f,0.f};

    #pragma unroll
    for (int ks = 0; ks < 4; ++ks) {
        const int kb = ks * 64 + g * 16;
        int c0 = wave * 32 + l15, c1 = c0 + 16;
        short8 a0 = *(const short8*)(sWb + ((c0 * 256 + kb) ^ ((c0 & 7) << 4)));
        short8 a1 = *(const short8*)(sWb + ((c1 * 256 + kb) ^ ((c1 & 7) << 4)));
        int t0 = l15, t1 = l15 + 16;
        short8 b0 = *(const short8*)(sXb + ((t0 * 256 + kb) ^ ((t0 & 7) << 4)));
        short8 b1 = *(const short8*)(sXb + ((t1 * 256 + kb) ^ ((t1 & 7) << 4)));
        acc00 = __builtin_amdgcn_mfma_f32_16x16x32_bf16(a0, b0, acc00, 0, 0, 0);
        acc01 = __builtin_amdgcn_mfma_f32_16x16x32_bf16(a0, b1, acc01, 0, 0, 0);
        acc10 = __builtin_amdgcn_mfma_f32_16x16x32_bf16(a1, b0, acc10, 0, 0, 0);
        acc11 = __builtin_amdgcn_mfma_f32_16x16x32_bf16(a1, b1, acc11, 0, 0, 0);
    }

    #pragma unroll
    for (int n = 0; n < 2; ++n) {
        int tok = n * 16 + l15;
        if (tok < nt) {
            int bg = pair_bg[start + tok];
            ushort* dst = yb2 + (size_t)bg * D + wave * 32 + g * 4;
            f32x4 v0 = (n == 0) ? acc00 : acc01;
            f32x4 v1 = (n == 0) ? acc10 : acc11;
            ushort4 p0 = { f2bf(v0[0]), f2bf(v0[1]), f2bf(v0[2]), f2bf(v0[3]) };
            ushort4 p1 = { f2bf(v1[0]), f2bf(v1[1]), f2bf(v1[2]), f2bf(v1[3]) };
            *(ushort4*)(dst)      = p0;
            *(ushort4*)(dst + 16) = p1;
        }
    }
}

// ---------------- final: out[b] = lrelu(sum_live yb2[b,slot]) f32 ----------------
__global__ __launch_bounds__(256) void moe_final_kernel(
    const ushort* __restrict__ yb2, const int* __restrict__ genres,
    float* __restrict__ out)
{
    int gid = blockIdx.x * 256 + threadIdx.x;   // BATCH*16 chunks of 8
    int b = gid >> 4, c8 = (gid & 15) * 8;
    int g0 = genres[b * NG + 0];
    int g1 = genres[b * NG + 1];
    int g2 = genres[b * NG + 2];

    float s[8] = {0,0,0,0,0,0,0,0};
    #pragma unroll
    for (int slot = 0; slot < NG; ++slot) {
        int g = (slot == 0) ? g0 : (slot == 1) ? g1 : g2;
        if (g != 0) {
            uint4 v = *(const uint4*)&yb2[((size_t)b * NG + slot) * D + c8];
            const unsigned w[4] = { v.x, v.y, v.z, v.w };
            #pragma unroll
            for (int j = 0; j < 4; ++j) {
                s[2*j]   += bf2f((ushort)(w[j] & 0xFFFF));
                s[2*j+1] += bf2f((ushort)(w[j] >> 16));
            }
        }
    }
    float r[8];
    #pragma unroll
    for (int j = 0; j < 8; ++j)
        r[j] = (s[j] >= 0.f) ? s[j] : 0.01f * s[j];
    float4 lo = { r[0], r[1], r[2], r[3] };
    float4 hi = { r[4], r[5], r[6], r[7] };
    *(float4*)&out[(size_t)b * D + c8]     = lo;
    *(float4*)&out[(size_t)b * D + c8 + 4] = hi;
}

// ---------------- fallback (round-0 kernel) if ws is too small ----------------
__global__ __launch_bounds__(128) void moe_layer_kernel(
    const float* __restrict__ x, const int* __restrict__ genres,
    const float* __restrict__ W, float* __restrict__ out)
{
    const int b = blockIdx.x;
    const int o = threadIdx.x;
    __shared__ float xs[D];
    xs[o] = x[(size_t)b * D + o];
    __syncthreads();
    int e0 = genres[b * NG + 0], e1 = genres[b * NG + 1], e2 = genres[b * NG + 2];
    float acc = 0.0f; int cnt = 0;
    #pragma unroll
    for (int g = 0; g < NG; ++g) {
        int e = (g == 0) ? e0 : (g == 1) ? e1 : e2;
        if (e != 0) {
            ++cnt;
            const float* We = W + (size_t)e * D * D + o;
            float a = 0.0f;
            #pragma unroll 8
            for (int i = 0; i < D; ++i) a = fmaf(xs[i], We[(size_t)i * D], a);
            acc += a;
        }
    }
    float r = (cnt > 0) ? (acc / (float)cnt) : 0.0f;
    out[(size_t)b * D + o] = (r >= 0.0f) ? r : 0.01f * r;
}

extern "C" void kernel_launch(void* const* d_in, const int* in_sizes, int n_in,
                              void* d_out, int out_size, void* d_ws, size_t ws_size,
                              hipStream_t stream)
{
    const float* x      = (const float*)d_in[0];
    const int*   genres = (const int*)d_in[1];
    const float* W0     = (const float*)d_in[2];
    const float* W1     = (const float*)d_in[3];
    float*       out    = (float*)d_out;

    if (ws_size < WS_REQUIRED) {
        moe_layer_kernel<<<BATCH, D, 0, stream>>>(x,   genres, W0, out);
        moe_layer_kernel<<<BATCH, D, 0, stream>>>(out, genres, W1, out);
        return;
    }

    char* ws = (char*)d_ws;
    int*    nTiles   = (int*)(ws + OFF_NT);
    int4*   tileInfo = (int4*)(ws + OFF_TILES);
    int*    hist_pb  = (int*)(ws + OFF_HISTPB);
    int*    pair_bg  = (int*)(ws + OFF_PAIR);
    ushort* Wt0      = (ushort*)(ws + OFF_WT0);
    ushort* Wt1      = (ushort*)(ws + OFF_WT1);
    ushort* yb       = (ushort*)(ws + OFF_YB);
    ushort* yb2      = (ushort*)(ws + OFF_YB2);

    moe_prep_kernel<<<128 + NHB, 256, 0, stream>>>(W0, W1, genres, Wt0, Wt1, hist_pb);
    moe_scatter_kernel<<<NHB, 256, 0, stream>>>(genres, hist_pb, pair_bg,
                                                nTiles, tileInfo);
    moe_gemm1_kernel<<<MAXT, 256, 0, stream>>>(x, genres, Wt0, pair_bg,
                                               tileInfo, nTiles, yb);
    moe_gemm2_kernel<<<MAXT, 256, 0, stream>>>(yb, genres, Wt1, pair_bg,
                                               tileInfo, nTiles, yb2);
    moe_final_kernel<<<BATCH * 16 / 256, 256, 0, stream>>>(yb2, genres, out);
}